// Round 1
// baseline (536.449 us; speedup 1.0000x reference)
//
#include <hip/hip_runtime.h>
#include <stdint.h>

#define BB 2
#define SS 2048
#define EE 1024
#define HH 16
#define DD 64

typedef _Float16 h16;
typedef _Float16 f16x8 __attribute__((ext_vector_type(8)));
typedef _Float16 f16x4 __attribute__((ext_vector_type(4)));
typedef float f32x4 __attribute__((ext_vector_type(4)));

// async global->LDS, 16B per lane. LDS dest = wave-uniform base + lane*16 (m104/m108).
__device__ __forceinline__ void async_ld16(const void* g, void* l) {
  __builtin_amdgcn_global_load_lds((__attribute__((address_space(1))) void*)g,
                                   (__attribute__((address_space(3))) void*)l,
                                   16, 0, 0);
}

// ---------------- f32 -> f16 convert (vectorized) ----------------
__global__ __launch_bounds__(256) void cvt_f16(const float* __restrict__ src,
                                               h16* __restrict__ dst, int n4) {
  int i = blockIdx.x * 256 + threadIdx.x;
  if (i >= n4) return;
  const float4 v = reinterpret_cast<const float4*>(src)[i];
  f16x4 o = {(_Float16)v.x, (_Float16)v.y, (_Float16)v.z, (_Float16)v.w};
  *reinterpret_cast<f16x4*>(dst + i * 4) = o;
}

// ---------------- GEMM: C[M=4096, N=1024] = A[M,K] * B[N,K]^T + bias ----------------
// tile 128x64, BK=64, 4 waves (2x2), wave tile 64x32. MODE 0: write [B,H,S,D] f16;
// MODE 1: write [B,H,D,S] f16 (V transposed); MODE 2: write f32 [M,N] (final output).
template <int MODE>
__global__ __launch_bounds__(256, 2) void gemm_bt(const h16* __restrict__ A,
                                                  const h16* __restrict__ Bw,
                                                  const float* __restrict__ bias,
                                                  void* __restrict__ out) {
  constexpr int K = EE;
  __shared__ h16 As[128 * 64];
  __shared__ h16 Bs[64 * 64];
  const int tid = threadIdx.x;
  const int lane = tid & 63, w = tid >> 6;
  const int cg = lane & 15, rg = lane >> 4;
  const int wr = w >> 1, wc = w & 1;
  const int row0 = blockIdx.y * 128, col0 = blockIdx.x * 64;

  f32x4 acc[4][2] = {};

  const h16* Ag = A + row0 * K;
  const h16* Bg = Bw + col0 * K;

  for (int k0 = 0; k0 < K; k0 += 64) {
#pragma unroll
    for (int i = 0; i < 4; ++i) {  // A: 128 rows x 64 k = 1024 16B-chunks
      int c = i * 256 + tid;
      async_ld16(Ag + (c >> 3) * K + k0 + (c & 7) * 8,
                 (char*)As + (i * 256 + w * 64) * 16);
    }
#pragma unroll
    for (int i = 0; i < 2; ++i) {  // B: 64 rows x 64 k = 512 chunks
      int c = i * 256 + tid;
      async_ld16(Bg + (c >> 3) * K + k0 + (c & 7) * 8,
                 (char*)Bs + (i * 256 + w * 64) * 16);
    }
    __syncthreads();  // compiler drains vmcnt(0) here
#pragma unroll
    for (int kk = 0; kk < 64; kk += 32) {
      f16x8 af[4], bfr[2];
#pragma unroll
      for (int m = 0; m < 4; ++m)
        af[m] = *(const f16x8*)&As[(wr * 64 + m * 16 + cg) * 64 + kk + rg * 8];
#pragma unroll
      for (int n = 0; n < 2; ++n)
        bfr[n] = *(const f16x8*)&Bs[(wc * 32 + n * 16 + cg) * 64 + kk + rg * 8];
#pragma unroll
      for (int m = 0; m < 4; ++m)
#pragma unroll
        for (int n = 0; n < 2; ++n)
          acc[m][n] = __builtin_amdgcn_mfma_f32_16x16x32_f16(af[m], bfr[n], acc[m][n], 0, 0, 0);
    }
    __syncthreads();
  }

  // C/D layout (verified m89/m91): col = lane&15, row = (lane>>4)*4 + j
#pragma unroll
  for (int n = 0; n < 2; ++n) {
    const int col = col0 + wc * 32 + n * 16 + cg;
    const float bv = bias[col];
#pragma unroll
    for (int m = 0; m < 4; ++m) {
#pragma unroll
      for (int j = 0; j < 4; ++j) {
        const int row = row0 + wr * 64 + m * 16 + rg * 4 + j;
        const float v = acc[m][n][j] + bv;
        if (MODE == 2) {
          ((float*)out)[row * EE + col] = v;
        } else {
          const int b = row >> 11, s = row & (SS - 1);
          const int h = col >> 6, d = col & (DD - 1);
          int idx;
          if (MODE == 0) idx = ((b * HH + h) * SS + s) * DD + d;   // [B,H,S,D]
          else           idx = ((b * HH + h) * DD + d) * SS + s;   // [B,H,D,S]
          ((h16*)out)[idx] = (_Float16)v;
        }
      }
    }
  }
}

// ---------------- flash attention fwd ----------------
// grid (S/64, B*H); block 256 = 4 waves; wave w owns 16 q-rows. KV tile = 64.
// Writes O in [B,S,H,D] (= [B,S,E]) f16 + per-row running max M and sum L (f32).
__global__ __launch_bounds__(256, 2) void attn_fwd(
    const h16* __restrict__ Qh, const h16* __restrict__ Kh, const h16* __restrict__ Vt,
    const int* __restrict__ mask, h16* __restrict__ O,
    float* __restrict__ Mrow, float* __restrict__ Lrow) {
  __shared__ h16 Ks[64 * 64];
  __shared__ h16 Vs[64 * 64];       // V^T tile: [d][s_k]
  __shared__ h16 Ps[4][16][72];     // per-wave P, padded row stride (144B, 16B-aligned)
  const int tid = threadIdx.x;
  const int lane = tid & 63, w = tid >> 6;
  const int cg = lane & 15, rg = lane >> 4;
  const int qt = blockIdx.x, bh = blockIdx.y;
  const int b = bh >> 4, h = bh & (HH - 1);
  const int q0 = qt * 64 + w * 16;

  // Q fragments (A-operand): row = lane&15, k = 8 contiguous at (lane>>4)*8
  const h16* Qbase = Qh + (bh * SS + q0 + cg) * DD;
  const f16x8 qf0 = *(const f16x8*)(Qbase + rg * 8);
  const f16x8 qf1 = *(const f16x8*)(Qbase + 32 + rg * 8);

  f32x4 o[4] = {};
  float mrun[4] = {-INFINITY, -INFINITY, -INFINITY, -INFINITY};
  float lrun[4] = {0.f, 0.f, 0.f, 0.f};

  const h16* Kg = Kh + bh * SS * DD;
  const h16* Vg = Vt + bh * DD * SS;
  const int* mbase = mask + (b * SS + q0) * SS;

  for (int k0 = 0; k0 < SS; k0 += 64) {
#pragma unroll
    for (int i = 0; i < 2; ++i) {
      int c = i * 256 + tid;
      async_ld16(Kg + (k0 + (c >> 3)) * DD + (c & 7) * 8,
                 (char*)Ks + (i * 256 + w * 64) * 16);
      async_ld16(Vg + (c >> 3) * SS + k0 + (c & 7) * 8,
                 (char*)Vs + (i * 256 + w * 64) * 16);
    }
    __syncthreads();

    // scores = Q K^T (same mfma order is reused bit-identically in avg kernel)
    f32x4 sc[4];
#pragma unroll
    for (int n = 0; n < 4; ++n) {
      f16x8 kf0 = *(const f16x8*)&Ks[(n * 16 + cg) * 64 + rg * 8];
      f16x8 kf1 = *(const f16x8*)&Ks[(n * 16 + cg) * 64 + 32 + rg * 8];
      f32x4 z = {};
      z = __builtin_amdgcn_mfma_f32_16x16x32_f16(qf0, kf0, z, 0, 0, 0);
      sc[n] = __builtin_amdgcn_mfma_f32_16x16x32_f16(qf1, kf1, z, 0, 0, 0);
    }

    // online softmax; row r = rg*4+j lives in the 16 lanes of group rg
#pragma unroll
    for (int j = 0; j < 4; ++j) {
      const int r = rg * 4 + j;
      const int* mrow = mbase + r * SS + k0;
      float v[4];
#pragma unroll
      for (int n = 0; n < 4; ++n)
        v[n] = mrow[n * 16 + cg] ? sc[n][j] * 0.125f : -1e9f;
      float tm = fmaxf(fmaxf(v[0], v[1]), fmaxf(v[2], v[3]));
      tm = fmaxf(tm, __shfl_xor(tm, 1));
      tm = fmaxf(tm, __shfl_xor(tm, 2));
      tm = fmaxf(tm, __shfl_xor(tm, 4));
      tm = fmaxf(tm, __shfl_xor(tm, 8));
      const float mn = fmaxf(mrun[j], tm);
      const float scale = __expf(mrun[j] - mn);
      float ps = 0.f;
#pragma unroll
      for (int n = 0; n < 4; ++n) {
        const float p = __expf(v[n] - mn);
        ps += p;
        Ps[w][r][n * 16 + cg] = (_Float16)p;
      }
      ps += __shfl_xor(ps, 1);
      ps += __shfl_xor(ps, 2);
      ps += __shfl_xor(ps, 4);
      ps += __shfl_xor(ps, 8);
      lrun[j] = lrun[j] * scale + ps;
      mrun[j] = mn;
#pragma unroll
      for (int n = 0; n < 4; ++n) o[n][j] *= scale;
    }
    __syncthreads();  // P visible (cross-lane via LDS)

    // O += P * V  (A = P row-major K-contig; B = V^T rows = d)
#pragma unroll
    for (int kkb = 0; kkb < 2; ++kkb) {
      f16x8 pa = *(const f16x8*)&Ps[w][cg][kkb * 32 + rg * 8];
#pragma unroll
      for (int n = 0; n < 4; ++n) {
        f16x8 vf = *(const f16x8*)&Vs[(n * 16 + cg) * 64 + kkb * 32 + rg * 8];
        o[n] = __builtin_amdgcn_mfma_f32_16x16x32_f16(pa, vf, o[n], 0, 0, 0);
      }
    }
    __syncthreads();
  }

  float rl[4];
#pragma unroll
  for (int j = 0; j < 4; ++j) rl[j] = 1.f / lrun[j];
#pragma unroll
  for (int n = 0; n < 4; ++n)
#pragma unroll
    for (int j = 0; j < 4; ++j) {
      const int s = q0 + rg * 4 + j;
      O[(b * SS + s) * EE + h * DD + n * 16 + cg] = (_Float16)(o[n][j] * rl[j]);
    }
  if (cg == 0) {
#pragma unroll
    for (int j = 0; j < 4; ++j) {
      const int s = q0 + rg * 4 + j;
      Mrow[bh * SS + s] = mrun[j];
      Lrow[bh * SS + s] = lrun[j];
    }
  }
}

// ---------------- avg_attn: mean over heads via score recompute ----------------
// grid (S/64 k, S/64 q, B); block 256; wave w owns 16 q-rows. No LDS, no barriers.
__global__ __launch_bounds__(256, 4) void avg_attn_k(
    const h16* __restrict__ Qh, const h16* __restrict__ Kh,
    const int* __restrict__ mask, const float* __restrict__ Mrow,
    const float* __restrict__ Lrow, float* __restrict__ outAvg) {
  const int tid = threadIdx.x;
  const int lane = tid & 63, w = tid >> 6;
  const int cg = lane & 15, rg = lane >> 4;
  const int kt = blockIdx.x, qt = blockIdx.y, b = blockIdx.z;
  const int q0 = qt * 64 + w * 16, k0 = kt * 64;

  unsigned mbits = 0;  // mask tile cached as bits (reused for all 16 heads)
#pragma unroll
  for (int j = 0; j < 4; ++j)
#pragma unroll
    for (int n = 0; n < 4; ++n)
      if (mask[(b * SS + q0 + rg * 4 + j) * SS + k0 + n * 16 + cg])
        mbits |= 1u << (j * 4 + n);

  f32x4 acc[4] = {};
  for (int h = 0; h < HH; ++h) {
    const int bh = b * HH + h;
    const h16* Qb = Qh + (bh * SS + q0 + cg) * DD;
    const f16x8 qf0 = *(const f16x8*)(Qb + rg * 8);
    const f16x8 qf1 = *(const f16x8*)(Qb + 32 + rg * 8);
    const h16* Kb = Kh + (bh * SS + k0) * DD;
    float Mv[4], Rv[4];
#pragma unroll
    for (int j = 0; j < 4; ++j) {
      const int s = q0 + rg * 4 + j;
      Mv[j] = Mrow[bh * SS + s];
      Rv[j] = 1.f / Lrow[bh * SS + s];
    }
#pragma unroll
    for (int n = 0; n < 4; ++n) {
      const f16x8 kf0 = *(const f16x8*)(Kb + (n * 16 + cg) * DD + rg * 8);
      const f16x8 kf1 = *(const f16x8*)(Kb + (n * 16 + cg) * DD + 32 + rg * 8);
      f32x4 z = {};
      z = __builtin_amdgcn_mfma_f32_16x16x32_f16(qf0, kf0, z, 0, 0, 0);
      const f32x4 sc = __builtin_amdgcn_mfma_f32_16x16x32_f16(qf1, kf1, z, 0, 0, 0);
#pragma unroll
      for (int j = 0; j < 4; ++j) {
        const float sv = ((mbits >> (j * 4 + n)) & 1u) ? sc[j] * 0.125f : -1e9f;
        acc[n][j] += __expf(sv - Mv[j]) * Rv[j];
      }
    }
  }
#pragma unroll
  for (int n = 0; n < 4; ++n)
#pragma unroll
    for (int j = 0; j < 4; ++j)
      outAvg[(b * SS + q0 + rg * 4 + j) * SS + k0 + n * 16 + cg] = acc[n][j] * 0.0625f;
}

// ---------------- launch ----------------
extern "C" void kernel_launch(void* const* d_in, const int* in_sizes, int n_in,
                              void* d_out, int out_size, void* d_ws, size_t ws_size,
                              hipStream_t stream) {
  const float* query = (const float*)d_in[0];
  const float* key_  = (const float*)d_in[1];
  const float* value = (const float*)d_in[2];
  const int*   mask  = (const int*)d_in[3];
  const float* Wq = (const float*)d_in[4];
  const float* bq = (const float*)d_in[5];
  const float* Wk = (const float*)d_in[6];
  const float* bk = (const float*)d_in[7];
  const float* Wv = (const float*)d_in[8];
  const float* bv = (const float*)d_in[9];
  const float* Wo = (const float*)d_in[10];
  const float* bo = (const float*)d_in[11];

  const size_t SZ_SE = (size_t)BB * SS * EE;  // 4,194,304
  h16* qx  = (h16*)d_ws;
  h16* kx  = qx + SZ_SE;
  h16* vx  = kx + SZ_SE;
  h16* wqx = vx + SZ_SE;
  h16* wkx = wqx + EE * EE;
  h16* wvx = wkx + EE * EE;
  h16* wox = wvx + EE * EE;
  h16* Qd  = wox + EE * EE;     // [B,H,S,D]
  h16* Kd  = Qd + SZ_SE;        // [B,H,S,D]
  h16* Vtd = Kd + SZ_SE;        // [B,H,D,S]
  h16* Od  = Vtd + SZ_SE;       // [B,S,E]
  float* Mr = (float*)(Od + SZ_SE);
  float* Lr = Mr + (size_t)BB * HH * SS;
  // total ws use: ~67.6 MB

  float* outp = (float*)d_out;
  float* avgp = outp + SZ_SE;

  cvt_f16<<<4096, 256, 0, stream>>>(query, qx, (int)(SZ_SE / 4));
  cvt_f16<<<4096, 256, 0, stream>>>(key_,  kx, (int)(SZ_SE / 4));
  cvt_f16<<<4096, 256, 0, stream>>>(value, vx, (int)(SZ_SE / 4));
  cvt_f16<<<1024, 256, 0, stream>>>(Wq, wqx, EE * EE / 4);
  cvt_f16<<<1024, 256, 0, stream>>>(Wk, wkx, EE * EE / 4);
  cvt_f16<<<1024, 256, 0, stream>>>(Wv, wvx, EE * EE / 4);
  cvt_f16<<<1024, 256, 0, stream>>>(Wo, wox, EE * EE / 4);

  gemm_bt<0><<<dim3(16, 32), 256, 0, stream>>>(qx, wqx, bq, Qd);
  gemm_bt<0><<<dim3(16, 32), 256, 0, stream>>>(kx, wkx, bk, Kd);
  gemm_bt<1><<<dim3(16, 32), 256, 0, stream>>>(vx, wvx, bv, Vtd);

  attn_fwd<<<dim3(SS / 64, BB * HH), 256, 0, stream>>>(Qd, Kd, Vtd, mask, Od, Mr, Lr);

  avg_attn_k<<<dim3(SS / 64, SS / 64, BB), 256, 0, stream>>>(Qd, Kd, mask, Mr, Lr, avgp);

  gemm_bt<2><<<dim3(16, 32), 256, 0, stream>>>(Od, wox, bo, outp);
}